// Round 3
// baseline (679.252 us; speedup 1.0000x reference)
//
#include <hip/hip_runtime.h>
#include <hip/hip_bf16.h>
#include <math.h>

#define FDIM 512
#define NEXP 4
#define HDIM 256
#define ADIM 32
#define BM   64
#define NTHR 512

typedef __attribute__((ext_vector_type(8))) short frag8;   // 8 bf16 (4 VGPR)
typedef __attribute__((ext_vector_type(4))) float f32x4;

// ws layout (ushort elements)
#define W1T_OFF 0                        // [4][256][512]  n-major
#define W2T_OFF (4*256*512)              // [4][32][256]   a-major
#define WGT_OFF (W2T_OFF + 4*32*256)     // [16][512]      rows 4..15 zero

__device__ inline ushort f2bf(float x) {
    union { float f; unsigned u; } v; v.f = x;
    unsigned r = v.u + 0x7FFFu + ((v.u >> 16) & 1u);   // RNE
    return (ushort)(r >> 16);
}

__device__ inline frag8 pack8(f32x4 a, f32x4 b) {
    frag8 r;
    r[0] = (short)f2bf(a[0]); r[1] = (short)f2bf(a[1]);
    r[2] = (short)f2bf(a[2]); r[3] = (short)f2bf(a[3]);
    r[4] = (short)f2bf(b[0]); r[5] = (short)f2bf(b[1]);
    r[6] = (short)f2bf(b[2]); r[7] = (short)f2bf(b[3]);
    return r;
}

// ---------------- prep: fp32 weights -> transposed bf16 in ws ----------------
__global__ __launch_bounds__(256) void moe_prep(const float* __restrict__ Wg,
                                                const float* __restrict__ W1,
                                                const float* __restrict__ W2,
                                                ushort* __restrict__ ws) {
    const int b = blockIdx.x, t = threadIdx.x;
    if (b < 64) {
        // W1[e][k][n] -> W1t[e][n][k]; 65536 octets over 16384 threads
        #pragma unroll
        for (int it = 0; it < 4; ++it) {
            int oct = (b * 256 + t) + it * 16384;
            int n = oct & 255, k8 = (oct >> 8) & 63, e = oct >> 14;
            f32x4 v0, v1;
            #pragma unroll
            for (int j = 0; j < 4; ++j) v0[j] = W1[(e*512 + k8*8 + j)*256 + n];
            #pragma unroll
            for (int j = 0; j < 4; ++j) v1[j] = W1[(e*512 + k8*8 + 4 + j)*256 + n];
            *(frag8*)(ws + W1T_OFF + (e*HDIM + n)*FDIM + k8*8) = pack8(v0, v1);
        }
    } else if (b < 80) {
        // W2[e][n][a] -> W2t[e][a][n]; 4096 octets
        int oct = (b - 64) * 256 + t;
        int a = oct & 31, n8 = (oct >> 5) & 31, e = oct >> 10;
        f32x4 v0, v1;
        #pragma unroll
        for (int j = 0; j < 4; ++j) v0[j] = W2[(e*HDIM + n8*8 + j)*ADIM + a];
        #pragma unroll
        for (int j = 0; j < 4; ++j) v1[j] = W2[(e*HDIM + n8*8 + 4 + j)*ADIM + a];
        *(frag8*)(ws + W2T_OFF + (e*ADIM + a)*HDIM + n8*8) = pack8(v0, v1);
    } else {
        // Wg[k][c] -> Wgt[c][k], c padded to 16 with zeros; 1024 octets
        int oct = (b - 80) * 256 + t;
        int k8 = oct & 63, c = oct >> 6;
        f32x4 v0 = {0,0,0,0}, v1 = {0,0,0,0};
        if (c < NEXP) {
            #pragma unroll
            for (int j = 0; j < 4; ++j) v0[j] = Wg[(k8*8 + j)*NEXP + c];
            #pragma unroll
            for (int j = 0; j < 4; ++j) v1[j] = Wg[(k8*8 + 4 + j)*NEXP + c];
        }
        *(frag8*)(ws + WGT_OFF + c*FDIM + k8*8) = pack8(v0, v1);
    }
}

// ---------------- main fused kernel ----------------
// LDS: fbuf 64KB (feat bf16 [64][512] swizzled) | hbuf 64KB ([2][64][256] swizzled) | gate 1KB
__global__ __launch_bounds__(NTHR, 2) void moe_main(
        const float* __restrict__ feat, const float* __restrict__ bg,
        const float* __restrict__ b1,  const float* __restrict__ b2,
        const ushort* __restrict__ ws, float* __restrict__ out) {
    __shared__ __attribute__((aligned(16))) unsigned char smem[65536 + 65536 + 1024];
    unsigned char* fbuf = smem;
    unsigned char* hbuf = smem + 65536;
    float* gate = (float*)(smem + 131072);

    const int tid = threadIdx.x;
    const int lane = tid & 63;
    const int wave = tid >> 6;        // 0..7
    const int l15 = lane & 15;
    const int lg  = lane >> 4;        // 0..3
    const int row0 = blockIdx.x * BM;
    const ushort* w1t = ws + W1T_OFF;
    const ushort* w2t = ws + W2T_OFF;
    const ushort* wgt = ws + WGT_OFF;

    // ---- stage features fp32 -> bf16 LDS (swizzle: byte ^= (row&7)<<4) ----
    {
        const float* fsrc = feat + (size_t)row0 * FDIM;
        #pragma unroll
        for (int it = 0; it < 8; ++it) {
            int c = tid + it * NTHR;          // 16B-chunk id, 0..4095
            int r = c >> 6, c8 = c & 63;
            const float* p = fsrc + r * FDIM + c8 * 8;
            f32x4 v0 = *(const f32x4*)p;
            f32x4 v1 = *(const f32x4*)(p + 4);
            *(frag8*)(fbuf + r * 1024 + ((c8 * 16) ^ ((r & 7) << 4))) = pack8(v0, v1);
        }
    }
    __syncthreads();

    // ---- gate logits via MFMA (waves 0..3, row-tile = wave) ----
    if (wave < 4) {
        const int rt = wave;
        const int arow = rt * 16 + l15;
        const int aswz = (arow & 7) << 4;
        f32x4 acc = {0.f, 0.f, 0.f, 0.f};
        #pragma unroll
        for (int s = 0; s < 16; ++s) {
            int k8 = s * 4 + lg;
            frag8 a = *(const frag8*)(fbuf + arow * 1024 + ((k8 * 16) ^ aswz));
            frag8 bb = *(const frag8*)(wgt + l15 * FDIM + k8 * 8);
            acc = __builtin_amdgcn_mfma_f32_16x16x32_bf16(a, bb, acc, 0, 0, 0);
        }
        if (l15 < NEXP) {
            float bgv = bg[l15];
            #pragma unroll
            for (int r = 0; r < 4; ++r)
                gate[(rt * 16 + lg * 4 + r) * 4 + l15] = acc[r] + bgv;
        }
    }
    __syncthreads();
    if (tid < BM) {   // softmax per row
        f32x4 g = *(const f32x4*)(gate + tid * 4);
        float m = fmaxf(fmaxf(g[0], g[1]), fmaxf(g[2], g[3]));
        float e0 = expf(g[0]-m), e1 = expf(g[1]-m), e2 = expf(g[2]-m), e3 = expf(g[3]-m);
        float inv = 1.f / (e0 + e1 + e2 + e3);
        f32x4 r = { e0*inv, e1*inv, e2*inv, e3*inv };
        *(f32x4*)(gate + tid * 4) = r;
    }
    __syncthreads();

    // GEMM2 tile assignment: wave -> (rt2 = wave>>1, ct2 = wave&1)
    const int rt2 = wave >> 1, ct2 = wave & 1;
    f32x4 gv[4];
    #pragma unroll
    for (int r = 0; r < 4; ++r)
        gv[r] = *(const f32x4*)(gate + (rt2 * 16 + lg * 4 + r) * 4);
    f32x4 act = {0.f, 0.f, 0.f, 0.f};

    // ---- expert-pair loop ----
    #pragma unroll
    for (int p = 0; p < 2; ++p) {
        f32x4 acc[2][4][2];   // [eo][rt][ct]
        #pragma unroll
        for (int eo = 0; eo < 2; ++eo)
            #pragma unroll
            for (int rt = 0; rt < 4; ++rt)
                #pragma unroll
                for (int ct = 0; ct < 2; ++ct)
                    acc[eo][rt][ct] = (f32x4){0.f, 0.f, 0.f, 0.f};

        // GEMM1: [64 x 512] x [512 x 32cols-per-wave] for 2 experts
        #pragma unroll 4
        for (int s = 0; s < 16; ++s) {
            int k8 = s * 4 + lg;
            frag8 a[4];
            #pragma unroll
            for (int rt = 0; rt < 4; ++rt) {
                int arow = rt * 16 + l15;
                a[rt] = *(const frag8*)(fbuf + arow * 1024 + ((k8 * 16) ^ ((arow & 7) << 4)));
            }
            frag8 bb[2][2];
            #pragma unroll
            for (int eo = 0; eo < 2; ++eo)
                #pragma unroll
                for (int ct = 0; ct < 2; ++ct) {
                    int col = (wave * 2 + ct) * 16 + l15;
                    bb[eo][ct] = *(const frag8*)(w1t + ((2*p + eo) * HDIM + col) * FDIM + k8 * 8);
                }
            #pragma unroll
            for (int eo = 0; eo < 2; ++eo)
                #pragma unroll
                for (int rt = 0; rt < 4; ++rt)
                    #pragma unroll
                    for (int ct = 0; ct < 2; ++ct)
                        acc[eo][rt][ct] = __builtin_amdgcn_mfma_f32_16x16x32_bf16(
                            a[rt], bb[eo][ct], acc[eo][rt][ct], 0, 0, 0);
        }

        __syncthreads();   // previous pair's GEMM2 reads of hbuf complete
        // h = relu(acc + b1) -> bf16 -> hbuf (swizzled)
        #pragma unroll
        for (int eo = 0; eo < 2; ++eo) {
            int e = 2 * p + eo;
            #pragma unroll
            for (int ct = 0; ct < 2; ++ct) {
                int col = (wave * 2 + ct) * 16 + l15;
                float bias = b1[e * HDIM + col];
                #pragma unroll
                for (int rt = 0; rt < 4; ++rt)
                    #pragma unroll
                    for (int r = 0; r < 4; ++r) {
                        int row = rt * 16 + lg * 4 + r;
                        float v = fmaxf(acc[eo][rt][ct][r] + bias, 0.f);
                        *(ushort*)(hbuf + eo * 32768 + row * 512 +
                                   ((2 * col) ^ ((row & 7) << 4))) = f2bf(v);
                    }
            }
        }
        __syncthreads();

        // GEMM2: out[64x32] per expert, gate-weighted accumulate
        #pragma unroll
        for (int eo = 0; eo < 2; ++eo) {
            int e = 2 * p + eo;
            const int arow = rt2 * 16 + l15;
            const int aswz = (arow & 7) << 4;
            const unsigned char* hb = hbuf + eo * 32768;
            f32x4 o = {0.f, 0.f, 0.f, 0.f};
            #pragma unroll
            for (int s = 0; s < 8; ++s) {
                int k8 = s * 4 + lg;
                frag8 a = *(const frag8*)(hb + arow * 512 + ((k8 * 16) ^ aswz));
                frag8 bb = *(const frag8*)(w2t + (e * ADIM + ct2 * 16 + l15) * HDIM + k8 * 8);
                o = __builtin_amdgcn_mfma_f32_16x16x32_bf16(a, bb, o, 0, 0, 0);
            }
            #pragma unroll
            for (int r = 0; r < 4; ++r)
                act[r] += gv[r][2*p + eo] * o[r];
        }
    }

    // ---- epilogue: + sum_e gate_e * b2[e] (softmax sums to 1), store ----
    {
        int col = ct2 * 16 + l15;
        float b2v0 = b2[0*ADIM + col], b2v1 = b2[1*ADIM + col];
        float b2v2 = b2[2*ADIM + col], b2v3 = b2[3*ADIM + col];
        #pragma unroll
        for (int r = 0; r < 4; ++r) {
            int row = row0 + rt2 * 16 + lg * 4 + r;
            float bs = gv[r][0]*b2v0 + gv[r][1]*b2v1 + gv[r][2]*b2v2 + gv[r][3]*b2v3;
            out[(size_t)row * ADIM + col] = act[r] + bs;
        }
    }
}

extern "C" void kernel_launch(void* const* d_in, const int* in_sizes, int n_in,
                              void* d_out, int out_size, void* d_ws, size_t ws_size,
                              hipStream_t stream) {
    const float* feat = (const float*)d_in[0];
    const float* Wg   = (const float*)d_in[1];
    const float* bg   = (const float*)d_in[2];
    const float* W1   = (const float*)d_in[3];
    const float* b1   = (const float*)d_in[4];
    const float* W2   = (const float*)d_in[5];
    const float* b2   = (const float*)d_in[6];
    float* out = (float*)d_out;
    ushort* ws = (ushort*)d_ws;

    moe_prep<<<84, 256, 0, stream>>>(Wg, W1, W2, ws);
    const int nblk = (131072 + BM - 1) / BM;   // 2048
    moe_main<<<nblk, NTHR, 0, stream>>>(feat, bg, b1, b2, ws, out);
}